// Round 1
// baseline (741.699 us; speedup 1.0000x reference)
//
#include <hip/hip_runtime.h>
#include <stdint.h>

#define B_ 8
#define C_ 256
#define N_ 4096
#define C8_ 32

typedef __attribute__((ext_vector_type(8))) short s16x8;
typedef __attribute__((ext_vector_type(4))) float f32x4;

static __device__ __forceinline__ unsigned short f2bf(float f) {
  union { float f; unsigned u; } v; v.f = f;
  unsigned r = v.u + 0x7FFFu + ((v.u >> 16) & 1u);
  return (unsigned short)(r >> 16);
}
static __device__ __forceinline__ float bf2f(unsigned short h) {
  union { unsigned u; float f; } v; v.u = ((unsigned)h) << 16;
  return v.f;
}

// ---- workspace offsets (bytes) ----
#define OFS_X1T  0ull
#define OFS_X2T  16777216ull
#define OFS_X11T 33554432ull
#define OFS_X21T 50331648ull
#define OFS_Q1   67108864ull
#define OFS_K1   69206016ull
#define OFS_Q2   71303168ull
#define OFS_K2   73400320ull
#define OFS_V1   75497472ull
#define OFS_V2   92274688ull
#define OFS_OA1  OFS_X1T   // x1T dead after conv
#define OFS_OA2  OFS_X2T
#define OFS_MM   109051904ull
#define OFS_WGT  109314048ull
#define OFS_W1B  109445120ull
#define OFS_WQB  109576192ull
#define OFS_WKB  109592576ull
#define OFS_WVB  109608960ull

// f32 [B][C][N] -> bf16 [B][N][C] (transpose + convert), z = b*2 + src
__global__ __launch_bounds__(256) void k_transpose(
    const float* __restrict__ x1, const float* __restrict__ x2,
    unsigned short* __restrict__ x1t, unsigned short* __restrict__ x2t) {
  __shared__ unsigned short lds[64 * 66];
  const int t = threadIdx.x;
  const int b = blockIdx.z >> 1, s = blockIdx.z & 1;
  const float* src = s ? x2 : x1;
  unsigned short* dst = s ? x2t : x1t;
  const int n0 = blockIdx.x * 64, c0 = blockIdx.y * 64;
  const int nl = t & 63;
#pragma unroll
  for (int r = 0; r < 16; ++r) {
    const int cl = (t >> 6) + 4 * r;
    lds[nl * 66 + cl] = f2bf(src[((size_t)(b * C_ + c0 + cl)) * N_ + n0 + nl]);
  }
  __syncthreads();
  const int c2 = t & 31;
#pragma unroll
  for (int r = 0; r < 8; ++r) {
    const int n = (t >> 5) + 8 * r;
    const unsigned uv = *(const unsigned*)(&lds[n * 66 + 2 * c2]);
    *(unsigned*)(&dst[((size_t)(b * N_ + n0 + n)) * C_ + c0 + 2 * c2]) = uv;
  }
}

__global__ __launch_bounds__(256) void k_wconv(
    const float* __restrict__ w1, const float* __restrict__ wq,
    const float* __restrict__ wk, const float* __restrict__ wv,
    unsigned short* __restrict__ w1b, unsigned short* __restrict__ wqb,
    unsigned short* __restrict__ wkb, unsigned short* __restrict__ wvb) {
  const int i = blockIdx.x * 256 + threadIdx.x;
  if (i < 65536) { w1b[i] = f2bf(w1[i]); wvb[i] = f2bf(wv[i]); }
  if (i < 8192)  { wqb[i] = f2bf(wq[i]); wkb[i] = f2bf(wk[i]); }
}

// OUT^T orientation: OUT[b][n][o] = sum_c X[b][n][c] * W[o][c] + bias[o]
// X bf16 [B][N][C]; W bf16 [M][C]; OUT bf16 [B][N][M], M = NF*16
template <int NF>
__global__ __launch_bounds__(256) void k_gemm_ot(
    const unsigned short* __restrict__ X, const unsigned short* __restrict__ W,
    const float* __restrict__ bias, unsigned short* __restrict__ OUT) {
  const int M = NF * 16;
  const int b = blockIdx.y;
  const int lane = threadIdx.x & 63, wave = threadIdx.x >> 6;
  const int li = lane & 15, g = lane >> 4;
  const int nbase = blockIdx.x * 64 + wave * 16;
  const f32x4 zero4 = {0.f, 0.f, 0.f, 0.f};
  f32x4 acc[NF];
#pragma unroll
  for (int f = 0; f < NF; ++f) acc[f] = zero4;
  const unsigned short* xrow = X + ((size_t)b * N_ + nbase + li) * C_ + 8 * g;
#pragma unroll
  for (int kk = 0; kk < 8; ++kk) {
    const s16x8 a = *(const s16x8*)(xrow + kk * 32);
#pragma unroll
    for (int f = 0; f < NF; ++f) {
      const s16x8 wf = *(const s16x8*)(W + ((size_t)(f * 16 + li)) * C_ + kk * 32 + 8 * g);
      acc[f] = __builtin_amdgcn_mfma_f32_16x16x32_bf16(a, wf, acc[f], 0, 0, 0);
    }
  }
#pragma unroll
  for (int f = 0; f < NF; ++f) {
    const float bb = bias[f * 16 + li];
#pragma unroll
    for (int r = 0; r < 4; ++r) {
      const int nrow = nbase + 4 * g + r;
      OUT[((size_t)b * N_ + nrow) * M + f * 16 + li] = f2bf(acc[f][r] + bb);
    }
  }
}

// OUT orientation (for V): OUT[b][o][n] = sum_c W[o][c] * X[b][n][c] + bias[o]
// OUT bf16 [B][C][N]
__global__ __launch_bounds__(256) void k_gemm_v(
    const unsigned short* __restrict__ X, const unsigned short* __restrict__ W,
    const float* __restrict__ bias, unsigned short* __restrict__ OUT) {
  const int b = blockIdx.z;
  const int lane = threadIdx.x & 63, wave = threadIdx.x >> 6;
  const int li = lane & 15, g = lane >> 4;
  const int obase = blockIdx.x * 64 + wave * 16;
  const int nbase = blockIdx.y * 256;
  const f32x4 zero4 = {0.f, 0.f, 0.f, 0.f};
  f32x4 acc[16];
#pragma unroll
  for (int f = 0; f < 16; ++f) acc[f] = zero4;
  const unsigned short* wrow = W + ((size_t)(obase + li)) * C_ + 8 * g;
#pragma unroll
  for (int kk = 0; kk < 8; ++kk) {
    const s16x8 a = *(const s16x8*)(wrow + kk * 32);
#pragma unroll
    for (int fn = 0; fn < 16; ++fn) {
      const s16x8 xf = *(const s16x8*)(X + ((size_t)b * N_ + nbase + fn * 16 + li) * C_ + kk * 32 + 8 * g);
      acc[fn] = __builtin_amdgcn_mfma_f32_16x16x32_bf16(a, xf, acc[fn], 0, 0, 0);
    }
  }
#pragma unroll
  for (int r = 0; r < 4; ++r) {
    const float bb = bias[obase + 4 * g + r];
#pragma unroll
    for (int fn = 0; fn < 16; ++fn) {
      OUT[((size_t)b * C_ + obase + 4 * g + r) * N_ + nbase + fn * 16 + li] = f2bf(acc[fn][r] + bb);
    }
  }
}

// Flash attention, swapped-QK^T, QBLK=64 (4 waves x 16 rows), KBLK=32.
// Q,K bf16 [B][N][32]; V bf16 [B][C][N]; OA bf16 [B][C][N] (softmax-normalized attn out)
__global__ __launch_bounds__(256) void k_flash(
    const unsigned short* __restrict__ Q, const unsigned short* __restrict__ K,
    const unsigned short* __restrict__ V, unsigned short* __restrict__ OA) {
  __shared__ unsigned short vtile[8192];  // [256 c][32 j] bf16, XOR-swizzled
  __shared__ unsigned short ptile[2048];  // per-wave [16 i][32 j] bf16, XOR-swizzled
  const int t = threadIdx.x;
  const int b = blockIdx.y;
  const int lane = t & 63, wave = t >> 6;
  const int li = lane & 15, g = lane >> 4;
  const int swz = (li & 7) << 4;
  const f32x4 zero4 = {0.f, 0.f, 0.f, 0.f};

  const s16x8 qf = *(const s16x8*)(Q + ((size_t)b * N_ + blockIdx.x * 64 + wave * 16 + li) * C8_ + 8 * g);

  f32x4 acc[16];
#pragma unroll
  for (int f = 0; f < 16; ++f) acc[f] = zero4;
  float m = -1e30f, lsum = 0.f;

  const int cl = t >> 2, ch = t & 3;
  const unsigned short* Vb = V + (size_t)b * C_ * N_;
  const unsigned short* Kb = K + (size_t)b * N_ * C8_;
  char* const pbase = (char*)ptile + wave * 1024;

  for (int jt = 0; jt < 128; ++jt) {
    const int jbase = jt * 32;
    __syncthreads();
#pragma unroll
    for (int rep = 0; rep < 4; ++rep) {
      const int c = cl + rep * 64;
      const int4 vv = *(const int4*)(Vb + (size_t)c * N_ + jbase + ch * 8);
      *(int4*)((char*)vtile + ((c * 64 + ch * 16) ^ ((c & 7) << 4))) = vv;
    }
    __syncthreads();

    const unsigned short* kp = Kb + (size_t)(jbase + li) * C8_ + 8 * g;
    const s16x8 k0 = *(const s16x8*)kp;
    const s16x8 k1 = *(const s16x8*)(kp + 16 * C8_);
    const f32x4 s0 = __builtin_amdgcn_mfma_f32_16x16x32_bf16(k0, qf, zero4, 0, 0, 0);
    const f32x4 s1 = __builtin_amdgcn_mfma_f32_16x16x32_bf16(k1, qf, zero4, 0, 0, 0);

    float tmax = fmaxf(fmaxf(fmaxf(s0[0], s0[1]), fmaxf(s0[2], s0[3])),
                       fmaxf(fmaxf(s1[0], s1[1]), fmaxf(s1[2], s1[3])));
    tmax = fmaxf(tmax, __shfl_xor(tmax, 16));
    tmax = fmaxf(tmax, __shfl_xor(tmax, 32));
    if (__any(tmax > m)) {  // deferred rescale: rare after warm-up
      const float mn = fmaxf(m, tmax);
      const float sc = __expf(m - mn);
#pragma unroll
      for (int f = 0; f < 16; ++f) {
        acc[f][0] *= sc; acc[f][1] *= sc; acc[f][2] *= sc; acc[f][3] *= sc;
      }
      lsum *= sc;
      m = mn;
    }
    const float p0 = __expf(s0[0] - m), p1 = __expf(s0[1] - m);
    const float p2 = __expf(s0[2] - m), p3 = __expf(s0[3] - m);
    const float p4 = __expf(s1[0] - m), p5 = __expf(s1[1] - m);
    const float p6 = __expf(s1[2] - m), p7 = __expf(s1[3] - m);
    float ps = ((p0 + p1) + (p2 + p3)) + ((p4 + p5) + (p6 + p7));
    ps += __shfl_xor(ps, 16);
    ps += __shfl_xor(ps, 32);
    lsum += ps;

    const unsigned w01 = (unsigned)f2bf(p0) | ((unsigned)f2bf(p1) << 16);
    const unsigned w23 = (unsigned)f2bf(p2) | ((unsigned)f2bf(p3) << 16);
    const unsigned w45 = (unsigned)f2bf(p4) | ((unsigned)f2bf(p5) << 16);
    const unsigned w67 = (unsigned)f2bf(p6) | ((unsigned)f2bf(p7) << 16);
    *(uint2*)(pbase + ((li * 64 + g * 8) ^ swz)) = make_uint2(w01, w23);
    *(uint2*)(pbase + ((li * 64 + 32 + g * 8) ^ swz)) = make_uint2(w45, w67);

    const s16x8 pb = *(const s16x8*)(pbase + ((li * 64 + g * 16) ^ swz));
#pragma unroll
    for (int fc = 0; fc < 16; ++fc) {
      const s16x8 vf = *(const s16x8*)((char*)vtile + (((fc * 16 + li) * 64 + g * 16) ^ swz));
      acc[fc] = __builtin_amdgcn_mfma_f32_16x16x32_bf16(vf, pb, acc[fc], 0, 0, 0);
    }
  }

  const float inv = 1.0f / lsum;
  unsigned short* oab = OA + (size_t)b * C_ * N_ + blockIdx.x * 64 + wave * 16 + li;
#pragma unroll
  for (int fc = 0; fc < 16; ++fc) {
#pragma unroll
    for (int r = 0; r < 4; ++r) {
      oab[(size_t)(fc * 16 + 4 * g + r) * N_] = f2bf(acc[fc][r] * inv);
    }
  }
}

// per-pixel mean/max over 512 concat channels; one wave per pixel row of x^T
__global__ __launch_bounds__(256) void k_sared(
    const unsigned short* __restrict__ x11t, const unsigned short* __restrict__ x21t,
    float* __restrict__ mm) {
  const int row = blockIdx.x * 4 + (threadIdx.x >> 6);
  const int lane = threadIdx.x & 63;
  float s = 0.f, mx = -1e30f;
  const uint2 a = *(const uint2*)(x11t + (size_t)row * C_ + lane * 4);
  const uint2 c = *(const uint2*)(x21t + (size_t)row * C_ + lane * 4);
  const unsigned vals[4] = {a.x, a.y, c.x, c.y};
#pragma unroll
  for (int k = 0; k < 4; ++k) {
    const float f0 = bf2f((unsigned short)(vals[k] & 0xffff));
    const float f1 = bf2f((unsigned short)(vals[k] >> 16));
    s += f0 + f1;
    mx = fmaxf(mx, fmaxf(f0, f1));
  }
#pragma unroll
  for (int off = 1; off < 64; off <<= 1) {
    s += __shfl_xor(s, off);
    mx = fmaxf(mx, __shfl_xor(mx, off));
  }
  if (lane == 0) {
    const int b = row >> 12, n = row & 4095;
    mm[(size_t)b * 8192 + n] = s * (1.f / 512.f);
    mm[(size_t)b * 8192 + 4096 + n] = mx;
  }
}

// 3x3 conv (2ch -> 1) + sigmoid
__global__ __launch_bounds__(256) void k_saconv(
    const float* __restrict__ mm, const float* __restrict__ wsa, float* __restrict__ wgt) {
  const int gi = blockIdx.x * 256 + threadIdx.x;
  const int b = gi >> 12, n = gi & 4095, h = n >> 6, w = n & 63;
  float acc = 0.f;
#pragma unroll
  for (int ky = 0; ky < 3; ++ky) {
#pragma unroll
    for (int kx = 0; kx < 3; ++kx) {
      const int hh = h + ky - 1, ww = w + kx - 1;
      if (hh >= 0 && hh < 64 && ww >= 0 && ww < 64) {
        const int nn = hh * 64 + ww;
        acc += mm[(size_t)b * 8192 + nn] * wsa[ky * 3 + kx];
        acc += mm[(size_t)b * 8192 + 4096 + nn] * wsa[9 + ky * 3 + kx];
      }
    }
  }
  wgt[gi] = 1.f / (1.f + __expf(-acc));
}

// out = weight * |x2*(g*oa2 + x21) - x1*(g*oa1 + x11)|
__global__ __launch_bounds__(256) void k_final(
    const float* __restrict__ x1, const float* __restrict__ x2,
    const unsigned short* __restrict__ x11t, const unsigned short* __restrict__ x21t,
    const unsigned short* __restrict__ oa1, const unsigned short* __restrict__ oa2,
    const float* __restrict__ wgt, const float* __restrict__ gamma,
    float* __restrict__ out) {
  __shared__ unsigned short t1[64 * 66], t2[64 * 66];
  const int t = threadIdx.x;
  const int b = blockIdx.z, c0 = blockIdx.y * 64, n0 = blockIdx.x * 64;
#pragma unroll
  for (int r = 0; r < 16; ++r) {
    const int nl = (t >> 6) + 4 * r, cl = t & 63;
    const size_t idx = ((size_t)b * N_ + n0 + nl) * C_ + c0 + cl;
    t1[nl * 66 + cl] = x11t[idx];
    t2[nl * 66 + cl] = x21t[idx];
  }
  __syncthreads();
  const float gam = gamma[0];
#pragma unroll
  for (int r = 0; r < 16; ++r) {
    const int cl = (t >> 6) + 4 * r, nl = t & 63;
    const size_t idx = ((size_t)b * C_ + c0 + cl) * N_ + n0 + nl;
    const float o1 = gam * bf2f(oa1[idx]) + bf2f(t1[nl * 66 + cl]);
    const float o2 = gam * bf2f(oa2[idx]) + bf2f(t2[nl * 66 + cl]);
    const float av = x1[idx] * o1;
    const float bv = x2[idx] * o2;
    out[idx] = wgt[(size_t)b * N_ + n0 + nl] * fabsf(bv - av);
  }
}

extern "C" void kernel_launch(void* const* d_in, const int* in_sizes, int n_in,
                              void* d_out, int out_size, void* d_ws, size_t ws_size,
                              hipStream_t stream) {
  const float* x1 = (const float*)d_in[0];
  const float* x2 = (const float*)d_in[1];
  const float* w1 = (const float*)d_in[2];
  const float* b1 = (const float*)d_in[3];
  const float* wq = (const float*)d_in[4];
  const float* bq = (const float*)d_in[5];
  const float* wk = (const float*)d_in[6];
  const float* bk = (const float*)d_in[7];
  const float* wv = (const float*)d_in[8];
  const float* bv = (const float*)d_in[9];
  const float* gamma = (const float*)d_in[10];
  const float* wsa = (const float*)d_in[11];
  float* out = (float*)d_out;
  char* ws = (char*)d_ws;

  unsigned short* x1T  = (unsigned short*)(ws + OFS_X1T);
  unsigned short* x2T  = (unsigned short*)(ws + OFS_X2T);
  unsigned short* x11T = (unsigned short*)(ws + OFS_X11T);
  unsigned short* x21T = (unsigned short*)(ws + OFS_X21T);
  unsigned short* Q1   = (unsigned short*)(ws + OFS_Q1);
  unsigned short* K1   = (unsigned short*)(ws + OFS_K1);
  unsigned short* Q2   = (unsigned short*)(ws + OFS_Q2);
  unsigned short* K2   = (unsigned short*)(ws + OFS_K2);
  unsigned short* V1   = (unsigned short*)(ws + OFS_V1);
  unsigned short* V2   = (unsigned short*)(ws + OFS_V2);
  unsigned short* oa1  = (unsigned short*)(ws + OFS_OA1);
  unsigned short* oa2  = (unsigned short*)(ws + OFS_OA2);
  float* mm  = (float*)(ws + OFS_MM);
  float* wgt = (float*)(ws + OFS_WGT);
  unsigned short* w1b = (unsigned short*)(ws + OFS_W1B);
  unsigned short* wqb = (unsigned short*)(ws + OFS_WQB);
  unsigned short* wkb = (unsigned short*)(ws + OFS_WKB);
  unsigned short* wvb = (unsigned short*)(ws + OFS_WVB);

  k_transpose<<<dim3(64, 4, 16), 256, 0, stream>>>(x1, x2, x1T, x2T);
  k_wconv<<<256, 256, 0, stream>>>(w1, wq, wk, wv, w1b, wqb, wkb, wvb);

  k_gemm_ot<16><<<dim3(64, 8), 256, 0, stream>>>(x1T, w1b, b1, x11T);
  k_gemm_ot<16><<<dim3(64, 8), 256, 0, stream>>>(x2T, w1b, b1, x21T);

  k_gemm_ot<2><<<dim3(64, 8), 256, 0, stream>>>(x11T, wqb, bq, Q1);
  k_gemm_ot<2><<<dim3(64, 8), 256, 0, stream>>>(x11T, wkb, bk, K1);
  k_gemm_ot<2><<<dim3(64, 8), 256, 0, stream>>>(x21T, wqb, bq, Q2);
  k_gemm_ot<2><<<dim3(64, 8), 256, 0, stream>>>(x21T, wkb, bk, K2);
  k_gemm_v<<<dim3(4, 16, 8), 256, 0, stream>>>(x11T, wvb, bv, V1);
  k_gemm_v<<<dim3(4, 16, 8), 256, 0, stream>>>(x21T, wvb, bv, V2);

  k_sared<<<8192, 256, 0, stream>>>(x11T, x21T, mm);
  k_saconv<<<128, 256, 0, stream>>>(mm, wsa, wgt);

  k_flash<<<dim3(64, 8), 256, 0, stream>>>(Q1, K1, V1, oa1);
  k_flash<<<dim3(64, 8), 256, 0, stream>>>(Q2, K2, V2, oa2);

  k_final<<<dim3(64, 4, 8), 256, 0, stream>>>(x1, x2, x11T, x21T, oa1, oa2, wgt, gamma, out);
}

// Round 2
// 557.978 us; speedup vs baseline: 1.3293x; 1.3293x over previous
//
#include <hip/hip_runtime.h>
#include <stdint.h>

#define B_ 8
#define C_ 256
#define N_ 4096
#define C8_ 32

typedef __attribute__((ext_vector_type(8))) short s16x8;
typedef __attribute__((ext_vector_type(4))) float f32x4;

static __device__ __forceinline__ unsigned short f2bf(float f) {
  union { float f; unsigned u; } v; v.f = f;
  unsigned r = v.u + 0x7FFFu + ((v.u >> 16) & 1u);
  return (unsigned short)(r >> 16);
}
static __device__ __forceinline__ float bf2f(unsigned short h) {
  union { unsigned u; float f; } v; v.u = ((unsigned)h) << 16;
  return v.f;
}

// ---- workspace offsets (bytes) ----
#define OFS_X1T  0ull
#define OFS_X2T  16777216ull
#define OFS_X11T 33554432ull
#define OFS_X21T 50331648ull
#define OFS_Q1   67108864ull
#define OFS_K1   69206016ull
#define OFS_Q2   71303168ull
#define OFS_K2   73400320ull
#define OFS_V1   75497472ull
#define OFS_V2   92274688ull
#define OFS_OA1  OFS_X1T   // x1T dead after conv
#define OFS_OA2  OFS_X2T
#define OFS_MM   109051904ull
#define OFS_WGT  109314048ull
#define OFS_W1B  109445120ull
#define OFS_WQB  109576192ull
#define OFS_WKB  109592576ull
#define OFS_WVB  109608960ull

// f32 [B][C][N] -> bf16 [B][N][C]
__global__ __launch_bounds__(256) void k_transpose(
    const float* __restrict__ x1, const float* __restrict__ x2,
    unsigned short* __restrict__ x1t, unsigned short* __restrict__ x2t) {
  __shared__ unsigned short lds[64 * 66];
  const int t = threadIdx.x;
  const int b = blockIdx.z >> 1, s = blockIdx.z & 1;
  const float* src = s ? x2 : x1;
  unsigned short* dst = s ? x2t : x1t;
  const int n0 = blockIdx.x * 64, c0 = blockIdx.y * 64;
  const int nl = t & 63;
#pragma unroll
  for (int r = 0; r < 16; ++r) {
    const int cl = (t >> 6) + 4 * r;
    lds[nl * 66 + cl] = f2bf(src[((size_t)(b * C_ + c0 + cl)) * N_ + n0 + nl]);
  }
  __syncthreads();
  const int c2 = t & 31;
#pragma unroll
  for (int r = 0; r < 8; ++r) {
    const int n = (t >> 5) + 8 * r;
    const unsigned uv = *(const unsigned*)(&lds[n * 66 + 2 * c2]);
    *(unsigned*)(&dst[((size_t)(b * N_ + n0 + n)) * C_ + c0 + 2 * c2]) = uv;
  }
}

__global__ __launch_bounds__(256) void k_wconv(
    const float* __restrict__ w1, const float* __restrict__ wq,
    const float* __restrict__ wk, const float* __restrict__ wv,
    unsigned short* __restrict__ w1b, unsigned short* __restrict__ wqb,
    unsigned short* __restrict__ wkb, unsigned short* __restrict__ wvb) {
  const int i = blockIdx.x * 256 + threadIdx.x;
  if (i < 65536) { w1b[i] = f2bf(w1[i]); wvb[i] = f2bf(wv[i]); }
  if (i < 8192)  { wqb[i] = f2bf(wq[i]); wkb[i] = f2bf(wk[i]); }
}

// conv1x1, OUT^T orientation, both sources (z = src). M = 256.
__global__ __launch_bounds__(256) void k_conv(
    const unsigned short* __restrict__ X1, const unsigned short* __restrict__ X2,
    const unsigned short* __restrict__ W, const float* __restrict__ bias,
    unsigned short* __restrict__ O1, unsigned short* __restrict__ O2) {
  const unsigned short* X = blockIdx.z ? X2 : X1;
  unsigned short* OUT = blockIdx.z ? O2 : O1;
  const int b = blockIdx.y;
  const int lane = threadIdx.x & 63, wave = threadIdx.x >> 6;
  const int li = lane & 15, g = lane >> 4;
  const int nbase = blockIdx.x * 64 + wave * 16;
  const f32x4 zero4 = {0.f, 0.f, 0.f, 0.f};
  f32x4 acc[16];
#pragma unroll
  for (int f = 0; f < 16; ++f) acc[f] = zero4;
  const unsigned short* xrow = X + ((size_t)b * N_ + nbase + li) * C_ + 8 * g;
#pragma unroll
  for (int kk = 0; kk < 8; ++kk) {
    const s16x8 a = *(const s16x8*)(xrow + kk * 32);
#pragma unroll
    for (int f = 0; f < 16; ++f) {
      const s16x8 wf = *(const s16x8*)(W + ((size_t)(f * 16 + li)) * C_ + kk * 32 + 8 * g);
      acc[f] = __builtin_amdgcn_mfma_f32_16x16x32_bf16(a, wf, acc[f], 0, 0, 0);
    }
  }
#pragma unroll
  for (int f = 0; f < 16; ++f) {
    const float bb = bias[f * 16 + li];
#pragma unroll
    for (int r = 0; r < 4; ++r) {
      OUT[((size_t)b * N_ + nbase + 4 * g + r) * C_ + f * 16 + li] = f2bf(acc[f][r] + bb);
    }
  }
}

// fused Q+K projection for one source (z = src); X read once.
__global__ __launch_bounds__(256) void k_qk(
    const unsigned short* __restrict__ X1, const unsigned short* __restrict__ X2,
    const unsigned short* __restrict__ WQ, const unsigned short* __restrict__ WK,
    const float* __restrict__ bq, const float* __restrict__ bk,
    unsigned short* __restrict__ Q1o, unsigned short* __restrict__ Q2o,
    unsigned short* __restrict__ K1o, unsigned short* __restrict__ K2o) {
  const unsigned short* X = blockIdx.z ? X2 : X1;
  unsigned short* Qo = blockIdx.z ? Q2o : Q1o;
  unsigned short* Ko = blockIdx.z ? K2o : K1o;
  const int b = blockIdx.y;
  const int lane = threadIdx.x & 63, wave = threadIdx.x >> 6;
  const int li = lane & 15, g = lane >> 4;
  const int nbase = blockIdx.x * 64 + wave * 16;
  const f32x4 zero4 = {0.f, 0.f, 0.f, 0.f};
  f32x4 aq[2], ak[2];
#pragma unroll
  for (int f = 0; f < 2; ++f) { aq[f] = zero4; ak[f] = zero4; }
  const unsigned short* xrow = X + ((size_t)b * N_ + nbase + li) * C_ + 8 * g;
#pragma unroll
  for (int kk = 0; kk < 8; ++kk) {
    const s16x8 a = *(const s16x8*)(xrow + kk * 32);
#pragma unroll
    for (int f = 0; f < 2; ++f) {
      const s16x8 wqf = *(const s16x8*)(WQ + ((size_t)(f * 16 + li)) * C_ + kk * 32 + 8 * g);
      const s16x8 wkf = *(const s16x8*)(WK + ((size_t)(f * 16 + li)) * C_ + kk * 32 + 8 * g);
      aq[f] = __builtin_amdgcn_mfma_f32_16x16x32_bf16(a, wqf, aq[f], 0, 0, 0);
      ak[f] = __builtin_amdgcn_mfma_f32_16x16x32_bf16(a, wkf, ak[f], 0, 0, 0);
    }
  }
#pragma unroll
  for (int f = 0; f < 2; ++f) {
    const float bbq = bq[f * 16 + li], bbk = bk[f * 16 + li];
#pragma unroll
    for (int r = 0; r < 4; ++r) {
      const size_t row = (size_t)b * N_ + nbase + 4 * g + r;
      Qo[row * C8_ + f * 16 + li] = f2bf(aq[f][r] + bbq);
      Ko[row * C8_ + f * 16 + li] = f2bf(ak[f][r] + bbk);
    }
  }
}

// V projection, OUT [B][C][N], both sources (z = b*2+src)
__global__ __launch_bounds__(256) void k_gemm_v(
    const unsigned short* __restrict__ X1, const unsigned short* __restrict__ X2,
    const unsigned short* __restrict__ W, const float* __restrict__ bias,
    unsigned short* __restrict__ V1o, unsigned short* __restrict__ V2o) {
  const int b = blockIdx.z >> 1, s = blockIdx.z & 1;
  const unsigned short* X = s ? X2 : X1;
  unsigned short* OUT = s ? V2o : V1o;
  const int lane = threadIdx.x & 63, wave = threadIdx.x >> 6;
  const int li = lane & 15, g = lane >> 4;
  const int obase = blockIdx.x * 64 + wave * 16;
  const int nbase = blockIdx.y * 256;
  const f32x4 zero4 = {0.f, 0.f, 0.f, 0.f};
  f32x4 acc[16];
#pragma unroll
  for (int f = 0; f < 16; ++f) acc[f] = zero4;
  const unsigned short* wrow = W + ((size_t)(obase + li)) * C_ + 8 * g;
#pragma unroll
  for (int kk = 0; kk < 8; ++kk) {
    const s16x8 a = *(const s16x8*)(wrow + kk * 32);
#pragma unroll
    for (int fn = 0; fn < 16; ++fn) {
      const s16x8 xf = *(const s16x8*)(X + ((size_t)b * N_ + nbase + fn * 16 + li) * C_ + kk * 32 + 8 * g);
      acc[fn] = __builtin_amdgcn_mfma_f32_16x16x32_bf16(a, xf, acc[fn], 0, 0, 0);
    }
  }
#pragma unroll
  for (int r = 0; r < 4; ++r) {
    const float bb = bias[obase + 4 * g + r];
#pragma unroll
    for (int fn = 0; fn < 16; ++fn) {
      OUT[((size_t)b * C_ + obase + 4 * g + r) * N_ + nbase + fn * 16 + li] = f2bf(acc[fn][r] + bb);
    }
  }
}

// Flash attention v2: merged sources, QBLK=128 (4 waves x 32 rows), KBLK=32,
// reg-staged double-buffered V, granule-XOR conflict-free LDS, defer-rescale.
__global__ __launch_bounds__(256, 2) void k_flash2(
    const unsigned short* __restrict__ Q1, const unsigned short* __restrict__ K1,
    const unsigned short* __restrict__ V1, unsigned short* __restrict__ OA1,
    const unsigned short* __restrict__ Q2, const unsigned short* __restrict__ K2,
    const unsigned short* __restrict__ V2, unsigned short* __restrict__ OA2) {
  __shared__ unsigned short vtile[2][8192];  // [256 c][4 granules of 8 j] swizzled
  __shared__ unsigned short ptile[4][1024];  // per wave [32 i][4 granules of 8 j]
  const int t = threadIdx.x;
  int f = blockIdx.x;
  f = (f & 7) * 64 + (f >> 3);               // XCD-bijective swizzle (512 = 8*64)
  const int z = f >> 5, qt = f & 31;
  const int b = z >> 1, src = z & 1;
  const unsigned short* Qp = src ? Q2 : Q1;
  const unsigned short* Kp = src ? K2 : K1;
  const unsigned short* Vp = src ? V2 : V1;
  unsigned short* OAp = (src ? OA2 : OA1) + (size_t)b * C_ * N_;

  const int lane = t & 63, wave = t >> 6;
  const int li = lane & 15, g = lane >> 4;
  const f32x4 zero4 = {0.f, 0.f, 0.f, 0.f};

  const unsigned short* Vb = Vp + (size_t)b * C_ * N_;
  const unsigned short* Kb = Kp + (size_t)b * N_ * C8_;
  const int qbase = qt * 128 + wave * 32;

  s16x8 qf[2];
#pragma unroll
  for (int ib = 0; ib < 2; ++ib)
    qf[ib] = *(const s16x8*)(Qp + ((size_t)b * N_ + qbase + ib * 16 + li) * C8_ + 8 * g);

  f32x4 acc[2][16];
#pragma unroll
  for (int ib = 0; ib < 2; ++ib)
#pragma unroll
    for (int fc = 0; fc < 16; ++fc) acc[ib][fc] = zero4;
  float m[2] = {-1e30f, -1e30f}, lsum[2] = {0.f, 0.f};

  const int vrow0 = t >> 2, vJ = t & 3;
  char* const pb = (char*)ptile[wave];
  const int swzp = (li & 3) << 4;

  // ---- prologue: tile 0 ----
  int4 vreg[4];
#pragma unroll
  for (int rep = 0; rep < 4; ++rep) {
    const int c = vrow0 + rep * 64;
    vreg[rep] = *(const int4*)(Vb + (size_t)c * N_ + vJ * 8);
  }
  s16x8 kf0, kf1;
  {
    const unsigned short* kp = Kb + (size_t)li * C8_ + 8 * g;
    kf0 = *(const s16x8*)kp;
    kf1 = *(const s16x8*)(kp + 16 * C8_);
  }
#pragma unroll
  for (int rep = 0; rep < 4; ++rep) {
    const int c = vrow0 + rep * 64;
    *(int4*)((char*)vtile[0] + c * 64 + (((vJ ^ (c & 3)) << 4))) = vreg[rep];
  }
  __syncthreads();

  for (int jt = 0; jt < 128; ++jt) {
    const int cur = jt & 1, nxt = cur ^ 1;
    const int jbn = ((jt + 1) & 127) * 32;  // wraps harmlessly at the end
    // issue next V tile loads (latency hidden under compute)
#pragma unroll
    for (int rep = 0; rep < 4; ++rep) {
      const int c = vrow0 + rep * 64;
      vreg[rep] = *(const int4*)(Vb + (size_t)c * N_ + jbn + vJ * 8);
    }
    // issue next K frags
    s16x8 kn0, kn1;
    {
      const unsigned short* kp = Kb + (size_t)(jbn + li) * C8_ + 8 * g;
      kn0 = *(const s16x8*)kp;
      kn1 = *(const s16x8*)(kp + 16 * C8_);
    }

    // ---- QK^T + softmax per i-block ----
#pragma unroll
    for (int ib = 0; ib < 2; ++ib) {
      const f32x4 s0 = __builtin_amdgcn_mfma_f32_16x16x32_bf16(kf0, qf[ib], zero4, 0, 0, 0);
      const f32x4 s1 = __builtin_amdgcn_mfma_f32_16x16x32_bf16(kf1, qf[ib], zero4, 0, 0, 0);
      float tmax = fmaxf(fmaxf(fmaxf(s0[0], s0[1]), fmaxf(s0[2], s0[3])),
                         fmaxf(fmaxf(s1[0], s1[1]), fmaxf(s1[2], s1[3])));
      tmax = fmaxf(tmax, __shfl_xor(tmax, 16));
      tmax = fmaxf(tmax, __shfl_xor(tmax, 32));
      if (__any(tmax - m[ib] > 8.0f)) {  // defer-rescale (T13)
        const float mn = fmaxf(m[ib], tmax);
        const float sc = __expf(m[ib] - mn);
#pragma unroll
        for (int fc = 0; fc < 16; ++fc) {
          acc[ib][fc][0] *= sc; acc[ib][fc][1] *= sc;
          acc[ib][fc][2] *= sc; acc[ib][fc][3] *= sc;
        }
        lsum[ib] *= sc;
        m[ib] = mn;
      }
      const float p0 = __expf(s0[0] - m[ib]), p1 = __expf(s0[1] - m[ib]);
      const float p2 = __expf(s0[2] - m[ib]), p3 = __expf(s0[3] - m[ib]);
      const float p4 = __expf(s1[0] - m[ib]), p5 = __expf(s1[1] - m[ib]);
      const float p6 = __expf(s1[2] - m[ib]), p7 = __expf(s1[3] - m[ib]);
      float ps = ((p0 + p1) + (p2 + p3)) + ((p4 + p5) + (p6 + p7));
      ps += __shfl_xor(ps, 16);
      ps += __shfl_xor(ps, 32);
      lsum[ib] += ps;

      const unsigned w01 = (unsigned)f2bf(p0) | ((unsigned)f2bf(p1) << 16);
      const unsigned w23 = (unsigned)f2bf(p2) | ((unsigned)f2bf(p3) << 16);
      const unsigned w45 = (unsigned)f2bf(p4) | ((unsigned)f2bf(p5) << 16);
      const unsigned w67 = (unsigned)f2bf(p6) | ((unsigned)f2bf(p7) << 16);
      const int r = ib * 16 + li;
      *(uint2*)(pb + r * 64 + ((((g >> 1) ^ (li & 3)) << 4) + (g & 1) * 8)) = make_uint2(w01, w23);
      *(uint2*)(pb + r * 64 + ((((2 + (g >> 1)) ^ (li & 3)) << 4) + (g & 1) * 8)) = make_uint2(w45, w67);
    }

    // ---- PV: V fragment reused across both i-blocks ----
    const s16x8 pb0 = *(const s16x8*)(pb + (0 * 16 + li) * 64 + ((g ^ (li & 3)) << 4));
    const s16x8 pb1 = *(const s16x8*)(pb + (1 * 16 + li) * 64 + ((g ^ (li & 3)) << 4));
    char* const vt = (char*)vtile[cur];
#pragma unroll
    for (int fc = 0; fc < 16; ++fc) {
      const s16x8 vf = *(const s16x8*)(vt + (fc * 16 + li) * 64 + ((g ^ (li & 3)) << 4));
      acc[0][fc] = __builtin_amdgcn_mfma_f32_16x16x32_bf16(vf, pb0, acc[0][fc], 0, 0, 0);
      acc[1][fc] = __builtin_amdgcn_mfma_f32_16x16x32_bf16(vf, pb1, acc[1][fc], 0, 0, 0);
    }

    // ---- write next V tile to LDS (waits only on this iter's V loads) ----
#pragma unroll
    for (int rep = 0; rep < 4; ++rep) {
      const int c = vrow0 + rep * 64;
      *(int4*)((char*)vtile[nxt] + c * 64 + (((vJ ^ (c & 3)) << 4))) = vreg[rep];
    }
    kf0 = kn0; kf1 = kn1;
    __syncthreads();
  }

  // ---- epilogue ----
#pragma unroll
  for (int ib = 0; ib < 2; ++ib) {
    const float inv = 1.0f / lsum[ib];
    unsigned short* oab = OAp + qbase + ib * 16 + li;
#pragma unroll
    for (int fc = 0; fc < 16; ++fc) {
#pragma unroll
      for (int r = 0; r < 4; ++r) {
        oab[(size_t)(fc * 16 + 4 * g + r) * N_] = f2bf(acc[ib][fc][r] * inv);
      }
    }
  }
}

// per-pixel mean/max over 512 concat channels
__global__ __launch_bounds__(256) void k_sared(
    const unsigned short* __restrict__ x11t, const unsigned short* __restrict__ x21t,
    float* __restrict__ mm) {
  const int row = blockIdx.x * 4 + (threadIdx.x >> 6);
  const int lane = threadIdx.x & 63;
  float s = 0.f, mx = -1e30f;
  const uint2 a = *(const uint2*)(x11t + (size_t)row * C_ + lane * 4);
  const uint2 c = *(const uint2*)(x21t + (size_t)row * C_ + lane * 4);
  const unsigned vals[4] = {a.x, a.y, c.x, c.y};
#pragma unroll
  for (int k = 0; k < 4; ++k) {
    const float f0 = bf2f((unsigned short)(vals[k] & 0xffff));
    const float f1 = bf2f((unsigned short)(vals[k] >> 16));
    s += f0 + f1;
    mx = fmaxf(mx, fmaxf(f0, f1));
  }
#pragma unroll
  for (int off = 1; off < 64; off <<= 1) {
    s += __shfl_xor(s, off);
    mx = fmaxf(mx, __shfl_xor(mx, off));
  }
  if (lane == 0) {
    const int b = row >> 12, n = row & 4095;
    mm[(size_t)b * 8192 + n] = s * (1.f / 512.f);
    mm[(size_t)b * 8192 + 4096 + n] = mx;
  }
}

__global__ __launch_bounds__(256) void k_saconv(
    const float* __restrict__ mm, const float* __restrict__ wsa, float* __restrict__ wgt) {
  const int gi = blockIdx.x * 256 + threadIdx.x;
  const int b = gi >> 12, n = gi & 4095, h = n >> 6, w = n & 63;
  float acc = 0.f;
#pragma unroll
  for (int ky = 0; ky < 3; ++ky) {
#pragma unroll
    for (int kx = 0; kx < 3; ++kx) {
      const int hh = h + ky - 1, ww = w + kx - 1;
      if (hh >= 0 && hh < 64 && ww >= 0 && ww < 64) {
        const int nn = hh * 64 + ww;
        acc += mm[(size_t)b * 8192 + nn] * wsa[ky * 3 + kx];
        acc += mm[(size_t)b * 8192 + 4096 + nn] * wsa[9 + ky * 3 + kx];
      }
    }
  }
  wgt[gi] = 1.f / (1.f + __expf(-acc));
}

// out = weight * |x2*(g*oa2 + x21) - x1*(g*oa1 + x11)|
__global__ __launch_bounds__(256) void k_final(
    const float* __restrict__ x1, const float* __restrict__ x2,
    const unsigned short* __restrict__ x11t, const unsigned short* __restrict__ x21t,
    const unsigned short* __restrict__ oa1, const unsigned short* __restrict__ oa2,
    const float* __restrict__ wgt, const float* __restrict__ gamma,
    float* __restrict__ out) {
  __shared__ unsigned short t1[64 * 66], t2[64 * 66];
  const int t = threadIdx.x;
  const int b = blockIdx.z, c0 = blockIdx.y * 64, n0 = blockIdx.x * 64;
#pragma unroll
  for (int r = 0; r < 16; ++r) {
    const int nl = (t >> 6) + 4 * r, cl = t & 63;
    const size_t idx = ((size_t)b * N_ + n0 + nl) * C_ + c0 + cl;
    t1[nl * 66 + cl] = x11t[idx];
    t2[nl * 66 + cl] = x21t[idx];
  }
  __syncthreads();
  const float gam = gamma[0];
#pragma unroll
  for (int r = 0; r < 16; ++r) {
    const int cl = (t >> 6) + 4 * r, nl = t & 63;
    const size_t idx = ((size_t)b * C_ + c0 + cl) * N_ + n0 + nl;
    const float o1 = gam * bf2f(oa1[idx]) + bf2f(t1[nl * 66 + cl]);
    const float o2 = gam * bf2f(oa2[idx]) + bf2f(t2[nl * 66 + cl]);
    const float av = x1[idx] * o1;
    const float bv = x2[idx] * o2;
    out[idx] = wgt[(size_t)b * N_ + n0 + nl] * fabsf(bv - av);
  }
}

extern "C" void kernel_launch(void* const* d_in, const int* in_sizes, int n_in,
                              void* d_out, int out_size, void* d_ws, size_t ws_size,
                              hipStream_t stream) {
  const float* x1 = (const float*)d_in[0];
  const float* x2 = (const float*)d_in[1];
  const float* w1 = (const float*)d_in[2];
  const float* b1 = (const float*)d_in[3];
  const float* wq = (const float*)d_in[4];
  const float* bq = (const float*)d_in[5];
  const float* wk = (const float*)d_in[6];
  const float* bk = (const float*)d_in[7];
  const float* wv = (const float*)d_in[8];
  const float* bv = (const float*)d_in[9];
  const float* gamma = (const float*)d_in[10];
  const float* wsa = (const float*)d_in[11];
  float* out = (float*)d_out;
  char* ws = (char*)d_ws;

  unsigned short* x1T  = (unsigned short*)(ws + OFS_X1T);
  unsigned short* x2T  = (unsigned short*)(ws + OFS_X2T);
  unsigned short* x11T = (unsigned short*)(ws + OFS_X11T);
  unsigned short* x21T = (unsigned short*)(ws + OFS_X21T);
  unsigned short* Q1   = (unsigned short*)(ws + OFS_Q1);
  unsigned short* K1   = (unsigned short*)(ws + OFS_K1);
  unsigned short* Q2   = (unsigned short*)(ws + OFS_Q2);
  unsigned short* K2   = (unsigned short*)(ws + OFS_K2);
  unsigned short* V1   = (unsigned short*)(ws + OFS_V1);
  unsigned short* V2   = (unsigned short*)(ws + OFS_V2);
  unsigned short* oa1  = (unsigned short*)(ws + OFS_OA1);
  unsigned short* oa2  = (unsigned short*)(ws + OFS_OA2);
  float* mm  = (float*)(ws + OFS_MM);
  float* wgt = (float*)(ws + OFS_WGT);
  unsigned short* w1b = (unsigned short*)(ws + OFS_W1B);
  unsigned short* wqb = (unsigned short*)(ws + OFS_WQB);
  unsigned short* wkb = (unsigned short*)(ws + OFS_WKB);
  unsigned short* wvb = (unsigned short*)(ws + OFS_WVB);

  k_transpose<<<dim3(64, 4, 16), 256, 0, stream>>>(x1, x2, x1T, x2T);
  k_wconv<<<256, 256, 0, stream>>>(w1, wq, wk, wv, w1b, wqb, wkb, wvb);

  k_conv<<<dim3(64, 8, 2), 256, 0, stream>>>(x1T, x2T, w1b, b1, x11T, x21T);
  k_qk<<<dim3(64, 8, 2), 256, 0, stream>>>(x11T, x21T, wqb, wkb, bq, bk, Q1, Q2, K1, K2);
  k_gemm_v<<<dim3(4, 16, 16), 256, 0, stream>>>(x11T, x21T, wvb, bv, V1, V2);

  k_sared<<<8192, 256, 0, stream>>>(x11T, x21T, mm);
  k_saconv<<<128, 256, 0, stream>>>(mm, wsa, wgt);

  k_flash2<<<512, 256, 0, stream>>>(Q1, K1, V1, oa1, Q2, K2, V2, oa2);

  k_final<<<dim3(64, 4, 8), 256, 0, stream>>>(x1, x2, x11T, x21T, oa1, oa2, wgt, gamma, out);
}